// Round 1
// baseline (171.132 us; speedup 1.0000x reference)
//
#include <hip/hip_runtime.h>
#include <cfloat>
#include <cmath>

#define NB   4
#define NPTS 4096
#define NLAT 512

// ---------------------------------------------------------------------------
// Kernel A: per-(mode, batch) nearest-distance mins.
//   mode 0: for each pred point,   min over targets   (d_p2t)
//   mode 1: for each target point, min over preds     (d_t2p)
//   mode 2: for each pred point,   min over preds, skip self (density NN)
// grid.x = 3 * NB * (NPTS/64); block = 256.
// Thread t: local point p = t>>2, j-segment seg = t&3 (interleaved j = 4*it+seg
// -> 4 distinct LDS addresses per wave spanning 64B = 16 banks, broadcast x16,
// conflict-free ds_read_b128).
// ---------------------------------------------------------------------------
__global__ __launch_bounds__(256) void k_min_dist(
    const float* __restrict__ pred_pos,
    const float* __restrict__ targ_pos,
    float* __restrict__ mins /* [3][NB][NPTS] */)
{
    __shared__ float4 lds[NPTS];   // 64 KiB

    const int tid   = threadIdx.x;
    const int chunk = blockIdx.x & 63;          // NPTS/64 = 64 chunks
    const int b     = (blockIdx.x >> 6) & 3;    // batch
    const int mode  = blockIdx.x >> 8;          // 0..2

    const float* pts    = (mode == 1) ? targ_pos : pred_pos;
    const float* others = (mode == 0) ? targ_pos : pred_pos;

    // Stage the full "others" set into LDS as padded float4.
    const float* ob = others + (size_t)b * NPTS * 3;
    for (int k = tid; k < NPTS; k += 256) {
        lds[k] = make_float4(ob[3*k+0], ob[3*k+1], ob[3*k+2], 0.f);
    }
    __syncthreads();

    const int p   = tid >> 2;                   // 0..63
    const int seg = tid & 3;
    const int i   = chunk * 64 + p;             // global point index
    const float* pp = pts + ((size_t)b * NPTS + i) * 3;
    const float px = pp[0], py = pp[1], pz = pp[2];
    const int skip = (mode == 2) ? i : -1;      // j never equals -1

    float m = FLT_MAX;
    #pragma unroll 8
    for (int it = 0; it < NPTS / 4; ++it) {
        const int j = (it << 2) + seg;
        const float4 o = lds[j];
        const float dx = px - o.x;
        const float dy = py - o.y;
        const float dz = pz - o.z;
        float d = fmaf(dx, dx, fmaf(dy, dy, dz * dz));
        d = (j == skip) ? FLT_MAX : d;
        m = fminf(m, d);
    }
    // combine the 4 j-segments (adjacent lanes, same wave)
    m = fminf(m, __shfl_xor(m, 1));
    m = fminf(m, __shfl_xor(m, 2));
    if (seg == 0)
        mins[((size_t)mode * NB + b) * NPTS + i] = m;
}

// ---------------------------------------------------------------------------
// Block-wide sum over 256 threads (4 waves).
// ---------------------------------------------------------------------------
__device__ __forceinline__ float block_sum(float v, float* red)
{
    #pragma unroll
    for (int o = 32; o >= 1; o >>= 1) v += __shfl_xor(v, o);
    const int w = threadIdx.x >> 6;
    __syncthreads();                 // protect red[] reuse across calls
    if ((threadIdx.x & 63) == 0) red[w] = v;
    __syncthreads();
    return red[0] + red[1] + red[2] + red[3];
}

// ---------------------------------------------------------------------------
// Kernel B: per-batch stats. grid = NB, block = 256.
//   cd_b      = (sum(p2t) + sum(t2p)) / NPTS
//   density_b = std(self_nn, ddof=1)   (two-pass, cancellation-safe)
// ---------------------------------------------------------------------------
__global__ __launch_bounds__(256) void k_batch_stats(
    const float* __restrict__ mins, float* __restrict__ part)
{
    __shared__ float red[4];
    const int b = blockIdx.x, tid = threadIdx.x;
    const float* p2t = mins + (size_t)0 * NB * NPTS + (size_t)b * NPTS;
    const float* t2p = mins + (size_t)1 * NB * NPTS + (size_t)b * NPTS;
    const float* slf = mins + (size_t)2 * NB * NPTS + (size_t)b * NPTS;

    float s1 = 0.f, s2 = 0.f, s3 = 0.f;
    for (int i = tid; i < NPTS; i += 256) {
        s1 += p2t[i]; s2 += t2p[i]; s3 += slf[i];
    }
    s1 = block_sum(s1, red);
    s2 = block_sum(s2, red);
    s3 = block_sum(s3, red);
    const float mean3 = s3 / (float)NPTS;

    float sv = 0.f;
    for (int i = tid; i < NPTS; i += 256) {
        const float d = slf[i] - mean3;
        sv += d * d;
    }
    sv = block_sum(sv, red);

    if (tid == 0) {
        part[b]      = (s1 + s2) / (float)NPTS;          // cd_b
        part[NB + b] = sqrtf(sv / (float)(NPTS - 1));    // density_b
    }
}

// ---------------------------------------------------------------------------
// Kernel C: KL + sizing MSE + final combine. grid = 1, block = 256.
// ---------------------------------------------------------------------------
__global__ __launch_bounds__(256) void k_finalize(
    const float* __restrict__ pred_sizing,
    const float* __restrict__ targ_sizing,
    const float* __restrict__ mu,
    const float* __restrict__ logvar,
    const float* __restrict__ part,
    float* __restrict__ out)
{
    __shared__ float red[4];
    const int tid = threadIdx.x;

    float kls = 0.f;
    for (int i = tid; i < NB * NLAT; i += 256) {
        const float lv = logvar[i], m = mu[i];
        kls += 1.f + lv - m * m - expf(lv);
    }
    float szs = 0.f;
    for (int i = tid; i < NB * NPTS; i += 256) {
        const float d = pred_sizing[i] - targ_sizing[i];
        szs += d * d;
    }
    kls = block_sum(kls, red);
    szs = block_sum(szs, red);

    if (tid == 0) {
        const float cd     = 0.25f * (part[0] + part[1] + part[2] + part[3]);
        const float dens   = 0.25f * (part[4] + part[5] + part[6] + part[7]);
        const float kl     = -0.5f * kls / (float)(NB * NLAT);
        const float sizing = szs / (float)(NB * NPTS);
        out[0] = cd + 0.001f * kl + 0.1f * dens + 0.05f * sizing;
    }
}

// ---------------------------------------------------------------------------
extern "C" void kernel_launch(void* const* d_in, const int* in_sizes, int n_in,
                              void* d_out, int out_size, void* d_ws, size_t ws_size,
                              hipStream_t stream)
{
    const float* pred_pos    = (const float*)d_in[0];
    const float* pred_sizing = (const float*)d_in[1];
    const float* targ_pos    = (const float*)d_in[2];
    const float* targ_sizing = (const float*)d_in[3];
    const float* mu          = (const float*)d_in[4];
    const float* logvar      = (const float*)d_in[5];

    float* mins = (float*)d_ws;                    // 3*NB*NPTS floats (192 KiB)
    float* part = mins + 3 * NB * NPTS;            // 2*NB floats

    k_min_dist<<<dim3(3 * NB * (NPTS / 64)), dim3(256), 0, stream>>>(
        pred_pos, targ_pos, mins);
    k_batch_stats<<<dim3(NB), dim3(256), 0, stream>>>(mins, part);
    k_finalize<<<dim3(1), dim3(256), 0, stream>>>(
        pred_sizing, targ_sizing, mu, logvar, part, (float*)d_out);
}

// Round 2
// 57.421 us; speedup vs baseline: 2.9803x; 2.9803x over previous
//
#include <hip/hip_runtime.h>
#include <cfloat>
#include <cmath>

#define NB     4
#define NPTS   4096
#define NLAT   512
#define RPTS   4                  // i-points per thread (register-blocked)
#define CJ     256                // j-chunk size staged in LDS
#define NJC    (NPTS / CJ)        // 16 j-chunks
#define ICH    (256 * RPTS)       // 1024 i-points per block
#define NIB    (NPTS / ICH)       // 4 i-blocks

// ---------------------------------------------------------------------------
// Kernel A: partial nearest-distance mins, j-split across blocks.
//   mode 0: pred -> target mins   mode 1: target -> pred mins
//   mode 2: pred -> pred (skip self)
// grid.x = 3 * NB * NIB * NJC = 768; block = 256.
// Each thread holds RPTS i-points in registers, scans CJ j-points from LDS
// (wave-uniform ds_read_b128 -> broadcast, conflict-free), then combines
// across j-chunks with uint atomicMin (sq-dists >= 0 so uint order == float).
// ---------------------------------------------------------------------------
__global__ __launch_bounds__(256) void k_min_dist(
    const float* __restrict__ pred_pos,
    const float* __restrict__ targ_pos,
    unsigned int* __restrict__ mins /* [3][NB][NPTS], pre-set to 0xFFFFFFFF */)
{
    __shared__ float4 lds[CJ];    // 4 KiB

    const int tid  = threadIdx.x;
    const int jc   = blockIdx.x & (NJC - 1);
    const int ib   = (blockIdx.x >> 4) & (NIB - 1);
    const int b    = (blockIdx.x >> 6) & 3;
    const int mode = blockIdx.x >> 8;

    const float* pts = (mode == 1) ? targ_pos : pred_pos;
    const float* oth = (mode == 0) ? targ_pos : pred_pos;

    // stage j-chunk (one float4 per thread)
    const int j0 = jc * CJ;
    const float* ob = oth + ((size_t)b * NPTS + j0) * 3;
    lds[tid] = make_float4(ob[3 * tid], ob[3 * tid + 1], ob[3 * tid + 2], 0.f);

    // load this thread's RPTS i-points into registers (coalesced-ish, once)
    const int i0 = ib * ICH + tid;            // + k*256
    const float* pb = pts + (size_t)b * NPTS * 3;
    float px[RPTS], py[RPTS], pz[RPTS], acc[RPTS];
    #pragma unroll
    for (int k = 0; k < RPTS; ++k) {
        const int i = i0 + k * 256;
        px[k] = pb[3 * i];
        py[k] = pb[3 * i + 1];
        pz[k] = pb[3 * i + 2];
        acc[k] = FLT_MAX;
    }
    __syncthreads();

    if (mode != 2) {
        #pragma unroll 4
        for (int j = 0; j < CJ; ++j) {
            const float4 o = lds[j];
            #pragma unroll
            for (int k = 0; k < RPTS; ++k) {
                const float dx = px[k] - o.x;
                const float dy = py[k] - o.y;
                const float dz = pz[k] - o.z;
                const float d  = fmaf(dx, dx, fmaf(dy, dy, dz * dz));
                acc[k] = fminf(acc[k], d);
            }
        }
    } else {
        #pragma unroll 4
        for (int j = 0; j < CJ; ++j) {
            const float4 o = lds[j];
            const int rel = (j0 + j) - i0;     // == k*256 iff j is self
            #pragma unroll
            for (int k = 0; k < RPTS; ++k) {
                const float dx = px[k] - o.x;
                const float dy = py[k] - o.y;
                const float dz = pz[k] - o.z;
                float d = fmaf(dx, dx, fmaf(dy, dy, dz * dz));
                d = (rel == k * 256) ? FLT_MAX : d;
                acc[k] = fminf(acc[k], d);
            }
        }
    }

    unsigned int* mbase = mins + ((size_t)mode * NB + b) * NPTS;
    #pragma unroll
    for (int k = 0; k < RPTS; ++k)
        atomicMin(&mbase[i0 + k * 256], __float_as_uint(acc[k]));
}

// ---------------------------------------------------------------------------
// Block-wide sum over 256 threads (4 waves).
// ---------------------------------------------------------------------------
__device__ __forceinline__ float block_sum(float v, float* red)
{
    #pragma unroll
    for (int o = 32; o >= 1; o >>= 1) v += __shfl_xor(v, o);
    const int w = threadIdx.x >> 6;
    __syncthreads();
    if ((threadIdx.x & 63) == 0) red[w] = v;
    __syncthreads();
    return red[0] + red[1] + red[2] + red[3];
}

// ---------------------------------------------------------------------------
// Kernel B: per-batch stats. grid = NB, block = 256.
// ---------------------------------------------------------------------------
__global__ __launch_bounds__(256) void k_batch_stats(
    const float* __restrict__ mins, float* __restrict__ part)
{
    __shared__ float red[4];
    const int b = blockIdx.x, tid = threadIdx.x;
    const float* p2t = mins + (size_t)0 * NB * NPTS + (size_t)b * NPTS;
    const float* t2p = mins + (size_t)1 * NB * NPTS + (size_t)b * NPTS;
    const float* slf = mins + (size_t)2 * NB * NPTS + (size_t)b * NPTS;

    float s1 = 0.f, s2 = 0.f, s3 = 0.f;
    for (int i = tid; i < NPTS; i += 256) {
        s1 += p2t[i]; s2 += t2p[i]; s3 += slf[i];
    }
    s1 = block_sum(s1, red);
    s2 = block_sum(s2, red);
    s3 = block_sum(s3, red);
    const float mean3 = s3 / (float)NPTS;

    float sv = 0.f;
    for (int i = tid; i < NPTS; i += 256) {
        const float d = slf[i] - mean3;
        sv += d * d;
    }
    sv = block_sum(sv, red);

    if (tid == 0) {
        part[b]      = (s1 + s2) / (float)NPTS;
        part[NB + b] = sqrtf(sv / (float)(NPTS - 1));
    }
}

// ---------------------------------------------------------------------------
// Kernel C: KL + sizing MSE + final combine. grid = 1, block = 256.
// ---------------------------------------------------------------------------
__global__ __launch_bounds__(256) void k_finalize(
    const float* __restrict__ pred_sizing,
    const float* __restrict__ targ_sizing,
    const float* __restrict__ mu,
    const float* __restrict__ logvar,
    const float* __restrict__ part,
    float* __restrict__ out)
{
    __shared__ float red[4];
    const int tid = threadIdx.x;

    float kls = 0.f;
    for (int i = tid; i < NB * NLAT; i += 256) {
        const float lv = logvar[i], m = mu[i];
        kls += 1.f + lv - m * m - expf(lv);
    }
    float szs = 0.f;
    for (int i = tid; i < NB * NPTS; i += 256) {
        const float d = pred_sizing[i] - targ_sizing[i];
        szs += d * d;
    }
    kls = block_sum(kls, red);
    szs = block_sum(szs, red);

    if (tid == 0) {
        const float cd     = 0.25f * (part[0] + part[1] + part[2] + part[3]);
        const float dens   = 0.25f * (part[4] + part[5] + part[6] + part[7]);
        const float kl     = -0.5f * kls / (float)(NB * NLAT);
        const float sizing = szs / (float)(NB * NPTS);
        out[0] = cd + 0.001f * kl + 0.1f * dens + 0.05f * sizing;
    }
}

// ---------------------------------------------------------------------------
extern "C" void kernel_launch(void* const* d_in, const int* in_sizes, int n_in,
                              void* d_out, int out_size, void* d_ws, size_t ws_size,
                              hipStream_t stream)
{
    const float* pred_pos    = (const float*)d_in[0];
    const float* pred_sizing = (const float*)d_in[1];
    const float* targ_pos    = (const float*)d_in[2];
    const float* targ_sizing = (const float*)d_in[3];
    const float* mu          = (const float*)d_in[4];
    const float* logvar      = (const float*)d_in[5];

    unsigned int* mins = (unsigned int*)d_ws;       // 3*NB*NPTS u32 (192 KiB)
    float* part = (float*)d_ws + 3 * NB * NPTS;     // 2*NB floats

    hipMemsetAsync(mins, 0xFF, (size_t)3 * NB * NPTS * sizeof(unsigned int),
                   stream);

    k_min_dist<<<dim3(3 * NB * NIB * NJC), dim3(256), 0, stream>>>(
        pred_pos, targ_pos, mins);
    k_batch_stats<<<dim3(NB), dim3(256), 0, stream>>>((const float*)mins, part);
    k_finalize<<<dim3(1), dim3(256), 0, stream>>>(
        pred_sizing, targ_sizing, mu, logvar, part, (float*)d_out);
}

// Round 3
// 52.357 us; speedup vs baseline: 3.2686x; 1.0967x over previous
//
#include <hip/hip_runtime.h>
#include <cfloat>
#include <cmath>

#define NB     4
#define NPTS   4096
#define NLAT   512
#define RPTS   4                  // i-points per thread (register-blocked)
#define CJ     256                // j-chunk size staged in LDS
#define NJC    (NPTS / CJ)        // 16 j-chunks
#define ICH    (256 * RPTS)       // 1024 i-points per block
#define NIB    (NPTS / ICH)       // 4 i-blocks

// ---------------------------------------------------------------------------
// Kernel A: partial nearest-distance mins, j-split across blocks.
//   mode 0: pred -> target     mode 1: target -> pred     mode 2: pred self
// grid.x = 3 * NB * NIB * NJC = 768; block = 256.
// LDS holds transformed points o' = (-2ox,-2oy,-2oz, |o|^2) so each pair is
// 3 FMA + 1 min (d = |p|^2 + (|o|^2 - 2 p.o); the |p|^2 term is a per-i
// constant added at store time). Each (mode,b,jc,i) partial is stored exactly
// once -> no init, no atomics, deterministic.
// ---------------------------------------------------------------------------
__global__ __launch_bounds__(256) void k_min_dist(
    const float* __restrict__ pred_pos,
    const float* __restrict__ targ_pos,
    float* __restrict__ part_mins /* [3][NB][NJC][NPTS] */)
{
    __shared__ float4 lds[CJ];    // 4 KiB

    const int tid  = threadIdx.x;
    const int jc   = blockIdx.x & (NJC - 1);
    const int ib   = (blockIdx.x >> 4) & (NIB - 1);
    const int b    = (blockIdx.x >> 6) & 3;
    const int mode = blockIdx.x >> 8;

    const float* pts = (mode == 1) ? targ_pos : pred_pos;
    const float* oth = (mode == 0) ? targ_pos : pred_pos;

    // stage transformed j-chunk (one point per thread)
    const int j0 = jc * CJ;
    {
        const float* ob = oth + ((size_t)b * NPTS + j0) * 3;
        const float ox = ob[3 * tid], oy = ob[3 * tid + 1], oz = ob[3 * tid + 2];
        const float o2 = fmaf(oz, oz, fmaf(oy, oy, ox * ox));
        lds[tid] = make_float4(-2.f * ox, -2.f * oy, -2.f * oz, o2);
    }

    // this thread's RPTS i-points
    const int i0 = ib * ICH + tid;            // + k*256
    const float* pb = pts + (size_t)b * NPTS * 3;
    float px[RPTS], py[RPTS], pz[RPTS], p2[RPTS], acc[RPTS];
    #pragma unroll
    for (int k = 0; k < RPTS; ++k) {
        const int i = i0 + k * 256;
        px[k] = pb[3 * i];
        py[k] = pb[3 * i + 1];
        pz[k] = pb[3 * i + 2];
        p2[k] = fmaf(pz[k], pz[k], fmaf(py[k], py[k], px[k] * px[k]));
        acc[k] = FLT_MAX;
    }
    __syncthreads();

    if (mode != 2) {
        #pragma unroll 4
        for (int j = 0; j < CJ; ++j) {
            const float4 o = lds[j];
            #pragma unroll
            for (int k = 0; k < RPTS; ++k) {
                float t = fmaf(o.x, px[k], o.w);
                t = fmaf(o.y, py[k], t);
                t = fmaf(o.z, pz[k], t);
                acc[k] = fminf(acc[k], t);
            }
        }
    } else {
        #pragma unroll 4
        for (int j = 0; j < CJ; ++j) {
            const float4 o = lds[j];
            const int rel = (j0 + j) - i0;     // == k*256 iff j is self
            #pragma unroll
            for (int k = 0; k < RPTS; ++k) {
                float t = fmaf(o.x, px[k], o.w);
                t = fmaf(o.y, py[k], t);
                t = fmaf(o.z, pz[k], t);
                t = (rel == k * 256) ? FLT_MAX : t;
                acc[k] = fminf(acc[k], t);
            }
        }
    }

    float* mbase = part_mins + (((size_t)mode * NB + b) * NJC + jc) * NPTS;
    #pragma unroll
    for (int k = 0; k < RPTS; ++k)
        mbase[i0 + k * 256] = acc[k] + p2[k];
}

// ---------------------------------------------------------------------------
// Block-wide sum over 256 threads (4 waves).
// ---------------------------------------------------------------------------
__device__ __forceinline__ float block_sum(float v, float* red)
{
    #pragma unroll
    for (int o = 32; o >= 1; o >>= 1) v += __shfl_xor(v, o);
    const int w = threadIdx.x >> 6;
    __syncthreads();
    if ((threadIdx.x & 63) == 0) red[w] = v;
    __syncthreads();
    return red[0] + red[1] + red[2] + red[3];
}

// ---------------------------------------------------------------------------
// Kernel B: per-batch stats. grid = NB, block = 256.
// Folds the NJC partials; caches self-NN mins in LDS for the two-pass std.
// ---------------------------------------------------------------------------
__global__ __launch_bounds__(256) void k_batch_stats(
    const float* __restrict__ part_mins, float* __restrict__ part)
{
    __shared__ float red[4];
    __shared__ float slf[NPTS];   // 16 KiB
    const int b = blockIdx.x, tid = threadIdx.x;
    const float* p0 = part_mins + (((size_t)0 * NB + b) * NJC) * NPTS;
    const float* p1 = part_mins + (((size_t)1 * NB + b) * NJC) * NPTS;
    const float* p2 = part_mins + (((size_t)2 * NB + b) * NJC) * NPTS;

    float s1 = 0.f, s2 = 0.f, s3 = 0.f;
    for (int i = tid; i < NPTS; i += 256) {
        float m1 = FLT_MAX, m2 = FLT_MAX, m3 = FLT_MAX;
        #pragma unroll
        for (int jc = 0; jc < NJC; ++jc) {
            m1 = fminf(m1, p0[jc * NPTS + i]);
            m2 = fminf(m2, p1[jc * NPTS + i]);
            m3 = fminf(m3, p2[jc * NPTS + i]);
        }
        s1 += m1; s2 += m2; s3 += m3;
        slf[i] = m3;
    }
    s1 = block_sum(s1, red);
    s2 = block_sum(s2, red);
    s3 = block_sum(s3, red);
    const float mean3 = s3 / (float)NPTS;

    float sv = 0.f;
    for (int i = tid; i < NPTS; i += 256) {
        const float d = slf[i] - mean3;
        sv += d * d;
    }
    sv = block_sum(sv, red);

    if (tid == 0) {
        part[b]      = (s1 + s2) / (float)NPTS;
        part[NB + b] = sqrtf(sv / (float)(NPTS - 1));
    }
}

// ---------------------------------------------------------------------------
// Kernel C: KL + sizing MSE + final combine. grid = 1, block = 256.
// ---------------------------------------------------------------------------
__global__ __launch_bounds__(256) void k_finalize(
    const float* __restrict__ pred_sizing,
    const float* __restrict__ targ_sizing,
    const float* __restrict__ mu,
    const float* __restrict__ logvar,
    const float* __restrict__ part,
    float* __restrict__ out)
{
    __shared__ float red[4];
    const int tid = threadIdx.x;

    float kls = 0.f;
    for (int i = tid; i < NB * NLAT; i += 256) {
        const float lv = logvar[i], m = mu[i];
        kls += 1.f + lv - m * m - expf(lv);
    }
    float szs = 0.f;
    for (int i = tid; i < NB * NPTS; i += 256) {
        const float d = pred_sizing[i] - targ_sizing[i];
        szs += d * d;
    }
    kls = block_sum(kls, red);
    szs = block_sum(szs, red);

    if (tid == 0) {
        const float cd     = 0.25f * (part[0] + part[1] + part[2] + part[3]);
        const float dens   = 0.25f * (part[4] + part[5] + part[6] + part[7]);
        const float kl     = -0.5f * kls / (float)(NB * NLAT);
        const float sizing = szs / (float)(NB * NPTS);
        out[0] = cd + 0.001f * kl + 0.1f * dens + 0.05f * sizing;
    }
}

// ---------------------------------------------------------------------------
extern "C" void kernel_launch(void* const* d_in, const int* in_sizes, int n_in,
                              void* d_out, int out_size, void* d_ws, size_t ws_size,
                              hipStream_t stream)
{
    const float* pred_pos    = (const float*)d_in[0];
    const float* pred_sizing = (const float*)d_in[1];
    const float* targ_pos    = (const float*)d_in[2];
    const float* targ_sizing = (const float*)d_in[3];
    const float* mu          = (const float*)d_in[4];
    const float* logvar      = (const float*)d_in[5];

    float* part_mins = (float*)d_ws;                        // 3*NB*NJC*NPTS f32 (3 MiB)
    float* part      = part_mins + (size_t)3 * NB * NJC * NPTS;  // 2*NB floats

    k_min_dist<<<dim3(3 * NB * NIB * NJC), dim3(256), 0, stream>>>(
        pred_pos, targ_pos, part_mins);
    k_batch_stats<<<dim3(NB), dim3(256), 0, stream>>>(part_mins, part);
    k_finalize<<<dim3(1), dim3(256), 0, stream>>>(
        pred_sizing, targ_sizing, mu, logvar, part, (float*)d_out);
}

// Round 4
// 46.623 us; speedup vs baseline: 3.6705x; 1.1230x over previous
//
#include <hip/hip_runtime.h>
#include <cfloat>
#include <cmath>

#define NB     4
#define NPTS   4096
#define NLAT   512
#define RPTS   16                 // i-points per thread (register-blocked)
#define CJ     64                 // j-chunk size staged in LDS
#define NJC    (NPTS / CJ)        // 64 j-chunks

// ---------------------------------------------------------------------------
// Kernel A: partial nearest-distance mins, j-split across blocks.
//   mode 0: pred -> target     mode 1: target -> pred     mode 2: pred self
// grid.x = 3 * NB * NJC = 768; block = 256. Each thread owns 16 i-points
// (stride 256), scans 64 j-points from LDS. Per j-iter: 1 ds_read_b128
// (uniform broadcast, 12 cyc LDS pipe) vs 64 VALU instr (128 cyc) -> VALU-
// bound (~37% LDS pipe). Pair math: o' = (-2o, |o|^2) staged, d = p2 +
// fma(oz,pz,fma(oy,py,fma(ox,px,o2))) -> 3 fma + 1 min per pair; per-i |p|^2
// added once at store. Each (mode,b,jc,i) partial stored exactly once.
// ---------------------------------------------------------------------------
__global__ __launch_bounds__(256) void k_min_dist(
    const float* __restrict__ pred_pos,
    const float* __restrict__ targ_pos,
    float* __restrict__ part_mins /* [3][NB][NJC][NPTS] */)
{
    __shared__ float4 lds[CJ];    // 1 KiB

    const int tid  = threadIdx.x;
    const int jc   = blockIdx.x & (NJC - 1);
    const int b    = (blockIdx.x >> 6) & 3;
    const int mode = blockIdx.x >> 8;

    const float* pts = (mode == 1) ? targ_pos : pred_pos;
    const float* oth = (mode == 0) ? targ_pos : pred_pos;

    const int j0 = jc * CJ;
    if (tid < CJ) {
        const float* ob = oth + ((size_t)b * NPTS + j0) * 3;
        const float ox = ob[3 * tid], oy = ob[3 * tid + 1], oz = ob[3 * tid + 2];
        const float o2 = fmaf(oz, oz, fmaf(oy, oy, ox * ox));
        lds[tid] = make_float4(-2.f * ox, -2.f * oy, -2.f * oz, o2);
    }

    const float* pb = pts + (size_t)b * NPTS * 3;
    float px[RPTS], py[RPTS], pz[RPTS], p2[RPTS], acc[RPTS];
    #pragma unroll
    for (int k = 0; k < RPTS; ++k) {
        const int i = tid + (k << 8);
        px[k] = pb[3 * i];
        py[k] = pb[3 * i + 1];
        pz[k] = pb[3 * i + 2];
        p2[k] = fmaf(pz[k], pz[k], fmaf(py[k], py[k], px[k] * px[k]));
        acc[k] = FLT_MAX;
    }
    __syncthreads();

    if (mode != 2) {
        #pragma unroll 2
        for (int j = 0; j < CJ; ++j) {
            const float4 o = lds[j];
            #pragma unroll
            for (int k = 0; k < RPTS; ++k) {
                float t = fmaf(o.x, px[k], o.w);
                t = fmaf(o.y, py[k], t);
                t = fmaf(o.z, pz[k], t);
                acc[k] = fminf(acc[k], t);
            }
        }
    } else {
        #pragma unroll 2
        for (int j = 0; j < CJ; ++j) {
            const float4 o = lds[j];
            const int rel = (j0 + j) - tid;    // == k<<8 iff j is self
            #pragma unroll
            for (int k = 0; k < RPTS; ++k) {
                float t = fmaf(o.x, px[k], o.w);
                t = fmaf(o.y, py[k], t);
                t = fmaf(o.z, pz[k], t);
                t = (rel == (k << 8)) ? FLT_MAX : t;
                acc[k] = fminf(acc[k], t);
            }
        }
    }

    float* mbase = part_mins + (((size_t)mode * NB + b) * NJC + jc) * NPTS;
    #pragma unroll
    for (int k = 0; k < RPTS; ++k)
        mbase[tid + (k << 8)] = acc[k] + p2[k];   // coalesced per k
}

// ---------------------------------------------------------------------------
// Block-wide sum over 256 threads (4 waves).
// ---------------------------------------------------------------------------
__device__ __forceinline__ float block_sum(float v, float* red)
{
    #pragma unroll
    for (int o = 32; o >= 1; o >>= 1) v += __shfl_xor(v, o);
    const int w = threadIdx.x >> 6;
    __syncthreads();
    if ((threadIdx.x & 63) == 0) red[w] = v;
    __syncthreads();
    return red[0] + red[1] + red[2] + red[3];
}

// ---------------------------------------------------------------------------
// Kernel B: fold NJC partials -> per-(mode,b,quarter) sum & sumsq.
// grid = 3*NB*4 = 48 blocks; block = 256. Each thread folds 4 i-points.
// Deterministic fixed-order reduction; variance later via E[x^2]-mu^2.
// ---------------------------------------------------------------------------
__global__ __launch_bounds__(256) void k_fold(
    const float* __restrict__ part_mins,
    float* __restrict__ sums /* [48] */,
    float* __restrict__ sumsqs /* [48] */)
{
    __shared__ float red[4];
    const int blk  = blockIdx.x;
    const int q    = blk & 3;
    const int b    = (blk >> 2) & 3;
    const int mode = blk >> 4;
    const float* base = part_mins + ((size_t)mode * NB + b) * NJC * NPTS;

    const int i0 = q * 1024 + threadIdx.x;     // + t*256, t<4
    float m[4] = {FLT_MAX, FLT_MAX, FLT_MAX, FLT_MAX};
    for (int jc = 0; jc < NJC; ++jc) {
        const float* row = base + (size_t)jc * NPTS + i0;
        #pragma unroll
        for (int t = 0; t < 4; ++t)
            m[t] = fminf(m[t], row[t * 256]);  // coalesced
    }
    float s = 0.f, s2 = 0.f;
    #pragma unroll
    for (int t = 0; t < 4; ++t) { s += m[t]; s2 = fmaf(m[t], m[t], s2); }

    s  = block_sum(s,  red);
    s2 = block_sum(s2, red);
    if (threadIdx.x == 0) { sums[blk] = s; sumsqs[blk] = s2; }
}

// ---------------------------------------------------------------------------
// Kernel C: KL + sizing MSE + final combine. grid = 1, block = 256.
// ---------------------------------------------------------------------------
__global__ __launch_bounds__(256) void k_finalize(
    const float* __restrict__ pred_sizing,
    const float* __restrict__ targ_sizing,
    const float* __restrict__ mu,
    const float* __restrict__ logvar,
    const float* __restrict__ sums,
    const float* __restrict__ sumsqs,
    float* __restrict__ out)
{
    __shared__ float red[4];
    const int tid = threadIdx.x;

    float kls = 0.f;
    for (int i = tid; i < NB * NLAT; i += 256) {
        const float lv = logvar[i], m = mu[i];
        kls += 1.f + lv - m * m - expf(lv);
    }
    float szs = 0.f;
    for (int i = tid; i < NB * NPTS; i += 256) {
        const float d = pred_sizing[i] - targ_sizing[i];
        szs += d * d;
    }
    kls = block_sum(kls, red);
    szs = block_sum(szs, red);

    if (tid == 0) {
        float cd_sum = 0.f, dens_sum = 0.f;
        for (int b = 0; b < NB; ++b) {
            float s01 = 0.f, sS = 0.f, sS2 = 0.f;
            for (int q = 0; q < 4; ++q) {
                s01 += sums[b * 4 + q] + sums[16 + b * 4 + q];
                sS  += sums[32 + b * 4 + q];
                sS2 += sumsqs[32 + b * 4 + q];
            }
            cd_sum += s01 / (float)NPTS;
            const float var = (sS2 - sS * sS / (float)NPTS) / (float)(NPTS - 1);
            dens_sum += sqrtf(fmaxf(var, 0.f));
        }
        const float cd     = cd_sum / (float)NB;
        const float dens   = dens_sum / (float)NB;
        const float kl     = -0.5f * kls / (float)(NB * NLAT);
        const float sizing = szs / (float)(NB * NPTS);
        out[0] = cd + 0.001f * kl + 0.1f * dens + 0.05f * sizing;
    }
}

// ---------------------------------------------------------------------------
extern "C" void kernel_launch(void* const* d_in, const int* in_sizes, int n_in,
                              void* d_out, int out_size, void* d_ws, size_t ws_size,
                              hipStream_t stream)
{
    const float* pred_pos    = (const float*)d_in[0];
    const float* pred_sizing = (const float*)d_in[1];
    const float* targ_pos    = (const float*)d_in[2];
    const float* targ_sizing = (const float*)d_in[3];
    const float* mu          = (const float*)d_in[4];
    const float* logvar      = (const float*)d_in[5];

    float* part_mins = (float*)d_ws;                             // 3*NB*NJC*NPTS f32 (12.6 MiB)
    float* sums      = part_mins + (size_t)3 * NB * NJC * NPTS;  // 48
    float* sumsqs    = sums + 48;                                // 48

    k_min_dist<<<dim3(3 * NB * NJC), dim3(256), 0, stream>>>(
        pred_pos, targ_pos, part_mins);
    k_fold<<<dim3(48), dim3(256), 0, stream>>>(part_mins, sums, sumsqs);
    k_finalize<<<dim3(1), dim3(256), 0, stream>>>(
        pred_sizing, targ_sizing, mu, logvar, sums, sumsqs, (float*)d_out);
}